// Round 3
// baseline (335.573 us; speedup 1.0000x reference)
//
#include <hip/hip_runtime.h>
#include <stdint.h>

typedef unsigned long long u64;

#define N_ 128
#define C_ 256
#define H_ 28
#define W_ 28
#define NPIX_ (N_ * H_ * W_)      // 100352 flat pixels
#define BN_EPS_ 1e-5f

// ---------------------------------------------------------------------------
// Kernel 1 (v3): bit-pack activations with COALESCED loads.
// thread = (pixel-pair p2, k-word). For j = 0..63: load float2 of channel
// c = k*64+j at pixels (2*p2, 2*p2+1) — consecutive lanes hit consecutive
// addresses (4 runs of 128B per wave instruction). Build both pixels' u64
// words in registers; no ballot, no transpose.
// xbits layout: [pixel][4] u64; bit c&63 of word c>>6 = (x[n,c,h,w] < 0).
// ---------------------------------------------------------------------------
__global__ __launch_bounds__(256) void pack_x_kernel(const float* __restrict__ x,
                                                     u64* __restrict__ xbits) {
    int tid = blockIdx.x * blockDim.x + threadIdx.x;
    if (tid >= (NPIX_ / 2) * 4) return;
    int k  = tid & 3;
    int p2 = tid >> 2;
    int g0 = p2 * 2;              // flat pixel = n*784 + hw  (pairs never cross n)
    int n  = g0 / (H_ * W_);
    int hw = g0 - n * (H_ * W_);
    const float* xp = x + ((size_t)n * C_ + (size_t)k * 64) * (H_ * W_) + hw;

    u64 b0 = 0, b1 = 0;
    #pragma unroll
    for (int j = 0; j < 64; ++j) {
        float2 f = *(const float2*)(xp + (size_t)j * (H_ * W_));
        b0 |= (u64)(f.x < 0.f) << j;
        b1 |= (u64)(f.y < 0.f) << j;
    }
    xbits[(size_t)g0 * 4 + k]       = b0;
    xbits[(size_t)(g0 + 1) * 4 + k] = b1;
}

// ---------------------------------------------------------------------------
// Kernel 2: bit-pack weights via wave ballot. wbits layout: [co][tap(9)][4].
// ---------------------------------------------------------------------------
__global__ __launch_bounds__(256) void pack_w_kernel(const float* __restrict__ w,
                                                     u64* __restrict__ wbits) {
    int gid  = blockIdx.x * blockDim.x + threadIdx.x;
    int wave = gid >> 6;
    int lane = gid & 63;
    if (wave >= C_ * 9 * 4) return;
    int k    = wave & 3;
    int rest = wave >> 2;     // co*9 + tap
    int tap  = rest % 9;
    int co   = rest / 9;
    int ci   = k * 64 + lane;
    float val = w[((size_t)co * C_ + ci) * 9 + tap];
    u64 mask = __ballot(val < 0.f);
    if (lane == 0) wbits[wave] = mask;
}

// ---------------------------------------------------------------------------
// Kernel 3: binarized conv + BN + hardtanh + residual.
// Block = (n, h); thread = co. Sliding-window column pipeline along w.
// Full unroll of the iw loop keeps sacc[] in registers (constant indices);
// __launch_bounds__(256,3) raises the VGPR cap (~168) so the 72-VGPR weight
// array stays resident instead of being re-materialized (round-2 pathology:
// VGPR_Count=64 → reload/addressing overhead ~2.7x the popcount core).
// ---------------------------------------------------------------------------
__global__ __launch_bounds__(256, 3) void conv_kernel(
    const u64* __restrict__ xbits, const u64* __restrict__ wbits,
    const float* __restrict__ x,
    const float* __restrict__ gamma, const float* __restrict__ beta,
    const float* __restrict__ mean, const float* __restrict__ var,
    float* __restrict__ out) {
    int nh = blockIdx.x;
    int h  = nh % H_;
    int n  = nh / H_;
    int co = threadIdx.x;

    __shared__ union {
        u64   lx[3][W_][4];       // 2688 B  (compute phase)
        float sout[C_][29];       // 29696 B (transpose phase)
    } sm;

    float inv  = gamma[co] / sqrtf(var[co] + BN_EPS_);
    float bias = beta[co] - mean[co] * inv;

    // Per-thread weight fragments: 9 taps x 4 u64 = 72 VGPRs.
    u64 wr[9][4];
    {
        const ulonglong2* wp = (const ulonglong2*)wbits + (size_t)co * 18;
        #pragma unroll
        for (int i = 0; i < 9; ++i) {
            ulonglong2 a = wp[i * 2];
            ulonglong2 b = wp[i * 2 + 1];
            wr[i][0] = a.x; wr[i][1] = a.y; wr[i][2] = b.x; wr[i][3] = b.y;
        }
    }

    // Stage 3 input bit-rows (336 u64) into LDS.
    for (int i = threadIdx.x; i < 3 * W_ * 4; i += 256) {
        int k    = i & 3;
        int rest = i >> 2;
        int ww   = rest % W_;
        int r    = rest / W_;
        int ih   = h - 1 + r;
        u64 v = 0;
        if (ih >= 0 && ih < H_)
            v = xbits[((size_t)(n * H_ + ih) * W_ + ww) * 4 + k];
        sm.lx[r][ww][k] = v;
    }
    __syncthreads();

    const bool row0 = (h > 0);
    const bool row2 = (h < H_ - 1);
    const int  nrows = 1 + (row0 ? 1 : 0) + (row2 ? 1 : 0);

    int sacc[W_];   // popcount sums per output w
    int pm = 0, pc = 0;

    #pragma unroll
    for (int iw = 0; iw < W_; ++iw) {
        int a0 = 0, a1 = 0, a2 = 0;
        u64 xw0, xw1, xw2, xw3;
        #define TAPROW(r, wb)                                                  \
            xw0 = sm.lx[r][iw][0]; xw1 = sm.lx[r][iw][1];                      \
            xw2 = sm.lx[r][iw][2]; xw3 = sm.lx[r][iw][3];                      \
            a0 += __popcll(xw0 ^ wr[wb+0][0]) + __popcll(xw1 ^ wr[wb+0][1]) +  \
                  __popcll(xw2 ^ wr[wb+0][2]) + __popcll(xw3 ^ wr[wb+0][3]);   \
            a1 += __popcll(xw0 ^ wr[wb+1][0]) + __popcll(xw1 ^ wr[wb+1][1]) +  \
                  __popcll(xw2 ^ wr[wb+1][2]) + __popcll(xw3 ^ wr[wb+1][3]);   \
            a2 += __popcll(xw0 ^ wr[wb+2][0]) + __popcll(xw1 ^ wr[wb+2][1]) +  \
                  __popcll(xw2 ^ wr[wb+2][2]) + __popcll(xw3 ^ wr[wb+2][3]);
        if (row0) { TAPROW(0, 0) }
        { TAPROW(1, 3) }
        if (row2) { TAPROW(2, 6) }
        #undef TAPROW
        if (iw >= 1) sacc[iw - 1] = pm + a2;
        pm = pc + a1;
        pc = a0;
    }
    sacc[W_ - 1] = pm;

    __syncthreads();   // done with lx before overwriting as sout

    // BN + hardtanh into the LDS transpose buffer.
    #pragma unroll
    for (int w = 0; w < W_; ++w) {
        int ncols = 3 - (w == 0 ? 1 : 0) - (w == W_ - 1 ? 1 : 0);
        int nv    = C_ * nrows * ncols;
        float convv = (float)(nv - 2 * sacc[w]);
        float val   = convv * inv + bias;
        val = fminf(1.f, fmaxf(-1.f, val));
        sm.sout[co][w] = val;
    }
    __syncthreads();

    // Coalesced residual add + store: contiguous 112B per (c) run.
    const float* xplane = x   + ((size_t)n * C_ * H_ + h) * W_;   // + c*H*W + w
    float*       oplane = out + ((size_t)n * C_ * H_ + h) * W_;
    for (int i = threadIdx.x; i < C_ * W_; i += 256) {
        int c    = i / W_;
        int wpos = i - c * W_;
        size_t g = (size_t)c * (H_ * W_) + wpos;
        oplane[g] = sm.sout[c][wpos] + xplane[g];
    }
}

// ---------------------------------------------------------------------------
extern "C" void kernel_launch(void* const* d_in, const int* in_sizes, int n_in,
                              void* d_out, int out_size, void* d_ws, size_t ws_size,
                              hipStream_t stream) {
    const float* x     = (const float*)d_in[0];
    const float* w     = (const float*)d_in[1];
    const float* gamma = (const float*)d_in[2];
    const float* beta  = (const float*)d_in[3];
    const float* mean  = (const float*)d_in[4];
    const float* var   = (const float*)d_in[5];
    float* out = (float*)d_out;

    u64* xbits = (u64*)d_ws;                                 // 100352*4 u64 = 3.21 MB
    u64* wbits = xbits + (size_t)NPIX_ * 4;                  // 256*9*4 u64 = 72 KB

    int pack_x_threads = (NPIX_ / 2) * 4;                    // 200704 → 784 blocks
    pack_x_kernel<<<(pack_x_threads + 255) / 256, 256, 0, stream>>>(x, xbits);
    pack_w_kernel<<<(C_ * 9 * 4 * 64) / 256, 256, 0, stream>>>(w, wbits);
    conv_kernel<<<N_ * H_, 256, 0, stream>>>(xbits, wbits, x, gamma, beta, mean, var, out);
}